// Round 19
// baseline (232.433 us; speedup 1.0000x reference)
//
#include <hip/hip_runtime.h>
#include <math.h>

#define B 32
#define N 16384
#define DIM 64
#define HID 64
#define KD 16
#define DM 512
#define MP 16

#define GRID_SAL 1024   // 4 blocks/CU; 512 contiguous points per block

typedef __attribute__((ext_vector_type(8))) _Float16 f16x8;
typedef __attribute__((ext_vector_type(2))) __fp16 fph2;   // cvt_pkrtz return type
typedef __attribute__((ext_vector_type(4))) float f32x4;

// tanh via exp + RAW v_rcp (no -ffast-math: '/' would emit the IEEE div sequence).
__device__ __forceinline__ float fast_tanh(float a) {
  const float e = __expf(2.f * a);
  return 1.f - 2.f * __builtin_amdgcn_rcpf(e + 1.f);
}

// ---------- single fused kernel: sal + partials; last block per row finishes ----------
__global__ __launch_bounds__(256) void k_all(
    const float* __restrict__ x, const float* __restrict__ W1,
    const float* __restrict__ b1, const float* __restrict__ w_s,
    float* __restrict__ y, float* __restrict__ tokens,
    const float* __restrict__ W_lift, const float* __restrict__ b_lift,
    const float* __restrict__ W_proj, const float* __restrict__ b_proj,
    const float* __restrict__ mu, const float* __restrict__ sigma,
    int* __restrict__ flags, float* __restrict__ pmax, float* __restrict__ psum,
    float* __restrict__ cval, int* __restrict__ cidx) {
  const int t = threadIdx.x;
  const int lane = t & 63, wvid = t >> 6;
  const int c16 = lane & 15, kq = lane >> 4;
  const int blk = blockIdx.x;
  const size_t pbase = (size_t)blk * 512;     // 512 contiguous points, one batch row

  // ---- prologue: W1 -> LDS fp16 hi/lo; w_s/b1 -> LDS ----
  __shared__ __align__(16) _Float16 lWh[64 * 72];
  __shared__ __align__(16) _Float16 lWl[64 * 72];
  __shared__ __align__(16) float lws[64], lb1[64];
  __shared__ float cv[4][16];  __shared__ int ci[4][16];   // per-wave top16
  __shared__ float sbm[4], sbs[4];
  __shared__ int s_old;
  // finisher scratch
  __shared__ float fm[32], fs[32], fwv[4], s_val[MP];
  __shared__ int fwi[4], s_idx[MP];
  __shared__ float lifted[MP][KD + 1];

#pragma unroll
  for (int j = 0; j < 16; ++j) {
    const int i = t + 256 * j;
    const int k = i >> 6, col = i & 63;
    const float v = W1[i];
    const _Float16 h = (_Float16)v;
    lWh[col * 72 + k] = h;
    lWl[col * 72 + k] = (_Float16)(v - (float)h);
  }
  if (t < 64) { lws[t] = w_s[t]; lb1[t] = b1[t]; }
  __syncthreads();

  f16x8 WH[8], WL[8];
#pragma unroll
  for (int ct = 0; ct < 4; ++ct)
#pragma unroll
    for (int kc = 0; kc < 2; ++kc) {
      const int off = (ct * 16 + c16) * 72 + kc * 32 + kq * 8;
      WH[ct * 2 + kc] = *(const f16x8*)(lWh + off);
      WL[ct * 2 + kc] = *(const f16x8*)(lWl + off);
    }

#define PKSPLIT(va, vb, HW, LW) {                                                  \
    const fph2 h_ = __builtin_amdgcn_cvt_pkrtz((va), (vb));                        \
    const fph2 l_ = __builtin_amdgcn_cvt_pkrtz((va) - (float)h_[0],                \
                                               (vb) - (float)h_[1]);               \
    HW = __builtin_bit_cast(unsigned, h_);                                         \
    LW = __builtin_bit_cast(unsigned, l_); }

#define LDX(b0, b1_, b2, b3, it_) {                                                \
    const size_t row_ = pbase + (it_) * 64 + wvid * 16 + c16;                      \
    const float* __restrict__ p_ = x + row_ * DIM + kq * 8;                        \
    b0 = *(const float4*)(p_);       b1_ = *(const float4*)(p_ + 4);               \
    b2 = *(const float4*)(p_ + 32);  b3 = *(const float4*)(p_ + 36); }

#define CMP(b0, b1_, b2, b3, it_, OUT) {                                           \
    f32x4 a0 = (f32x4)0.f, a1 = (f32x4)0.f, a2 = (f32x4)0.f, a3 = (f32x4)0.f;      \
    { uint4 H, L;                                                                  \
      PKSPLIT(b0.x, b0.y, H.x, L.x); PKSPLIT(b0.z, b0.w, H.y, L.y);                \
      PKSPLIT(b1_.x, b1_.y, H.z, L.z); PKSPLIT(b1_.z, b1_.w, H.w, L.w);            \
      const f16x8 bh = __builtin_bit_cast(f16x8, H);                               \
      const f16x8 bl = __builtin_bit_cast(f16x8, L);                               \
      a0 = __builtin_amdgcn_mfma_f32_16x16x32_f16(WH[0], bh, a0, 0, 0, 0);         \
      a1 = __builtin_amdgcn_mfma_f32_16x16x32_f16(WH[2], bh, a1, 0, 0, 0);         \
      a2 = __builtin_amdgcn_mfma_f32_16x16x32_f16(WH[4], bh, a2, 0, 0, 0);         \
      a3 = __builtin_amdgcn_mfma_f32_16x16x32_f16(WH[6], bh, a3, 0, 0, 0);         \
      a0 = __builtin_amdgcn_mfma_f32_16x16x32_f16(WL[0], bh, a0, 0, 0, 0);         \
      a1 = __builtin_amdgcn_mfma_f32_16x16x32_f16(WL[2], bh, a1, 0, 0, 0);         \
      a2 = __builtin_amdgcn_mfma_f32_16x16x32_f16(WL[4], bh, a2, 0, 0, 0);         \
      a3 = __builtin_amdgcn_mfma_f32_16x16x32_f16(WL[6], bh, a3, 0, 0, 0);         \
      a0 = __builtin_amdgcn_mfma_f32_16x16x32_f16(WH[0], bl, a0, 0, 0, 0);         \
      a1 = __builtin_amdgcn_mfma_f32_16x16x32_f16(WH[2], bl, a1, 0, 0, 0);         \
      a2 = __builtin_amdgcn_mfma_f32_16x16x32_f16(WH[4], bl, a2, 0, 0, 0);         \
      a3 = __builtin_amdgcn_mfma_f32_16x16x32_f16(WH[6], bl, a3, 0, 0, 0); }       \
    { uint4 H, L;                                                                  \
      PKSPLIT(b2.x, b2.y, H.x, L.x); PKSPLIT(b2.z, b2.w, H.y, L.y);                \
      PKSPLIT(b3.x, b3.y, H.z, L.z); PKSPLIT(b3.z, b3.w, H.w, L.w);                \
      const f16x8 bh = __builtin_bit_cast(f16x8, H);                               \
      const f16x8 bl = __builtin_bit_cast(f16x8, L);                               \
      a0 = __builtin_amdgcn_mfma_f32_16x16x32_f16(WH[1], bh, a0, 0, 0, 0);         \
      a1 = __builtin_amdgcn_mfma_f32_16x16x32_f16(WH[3], bh, a1, 0, 0, 0);         \
      a2 = __builtin_amdgcn_mfma_f32_16x16x32_f16(WH[5], bh, a2, 0, 0, 0);         \
      a3 = __builtin_amdgcn_mfma_f32_16x16x32_f16(WH[7], bh, a3, 0, 0, 0);         \
      a0 = __builtin_amdgcn_mfma_f32_16x16x32_f16(WL[1], bh, a0, 0, 0, 0);         \
      a1 = __builtin_amdgcn_mfma_f32_16x16x32_f16(WL[3], bh, a1, 0, 0, 0);         \
      a2 = __builtin_amdgcn_mfma_f32_16x16x32_f16(WL[5], bh, a2, 0, 0, 0);         \
      a3 = __builtin_amdgcn_mfma_f32_16x16x32_f16(WL[7], bh, a3, 0, 0, 0);         \
      a0 = __builtin_amdgcn_mfma_f32_16x16x32_f16(WH[1], bl, a0, 0, 0, 0);         \
      a1 = __builtin_amdgcn_mfma_f32_16x16x32_f16(WH[3], bl, a1, 0, 0, 0);         \
      a2 = __builtin_amdgcn_mfma_f32_16x16x32_f16(WH[5], bl, a2, 0, 0, 0);         \
      a3 = __builtin_amdgcn_mfma_f32_16x16x32_f16(WH[7], bl, a3, 0, 0, 0); }       \
    float s = 0.f;                                                                 \
    { const f32x4 wv = *(const f32x4*)(lws + kq * 4);                              \
      const f32x4 bv = *(const f32x4*)(lb1 + kq * 4);                              \
      s = fmaf(wv[0], fast_tanh(a0[0] + bv[0]), s);                                \
      s = fmaf(wv[1], fast_tanh(a0[1] + bv[1]), s);                                \
      s = fmaf(wv[2], fast_tanh(a0[2] + bv[2]), s);                                \
      s = fmaf(wv[3], fast_tanh(a0[3] + bv[3]), s); }                              \
    { const f32x4 wv = *(const f32x4*)(lws + 16 + kq * 4);                         \
      const f32x4 bv = *(const f32x4*)(lb1 + 16 + kq * 4);                         \
      s = fmaf(wv[0], fast_tanh(a1[0] + bv[0]), s);                                \
      s = fmaf(wv[1], fast_tanh(a1[1] + bv[1]), s);                                \
      s = fmaf(wv[2], fast_tanh(a1[2] + bv[2]), s);                                \
      s = fmaf(wv[3], fast_tanh(a1[3] + bv[3]), s); }                              \
    { const f32x4 wv = *(const f32x4*)(lws + 32 + kq * 4);                         \
      const f32x4 bv = *(const f32x4*)(lb1 + 32 + kq * 4);                         \
      s = fmaf(wv[0], fast_tanh(a2[0] + bv[0]), s);                                \
      s = fmaf(wv[1], fast_tanh(a2[1] + bv[1]), s);                                \
      s = fmaf(wv[2], fast_tanh(a2[2] + bv[2]), s);                                \
      s = fmaf(wv[3], fast_tanh(a2[3] + bv[3]), s); }                              \
    { const f32x4 wv = *(const f32x4*)(lws + 48 + kq * 4);                         \
      const f32x4 bv = *(const f32x4*)(lb1 + 48 + kq * 4);                         \
      s = fmaf(wv[0], fast_tanh(a3[0] + bv[0]), s);                                \
      s = fmaf(wv[1], fast_tanh(a3[1] + bv[1]), s);                                \
      s = fmaf(wv[2], fast_tanh(a3[2] + bv[2]), s);                                \
      s = fmaf(wv[3], fast_tanh(a3[3] + bv[3]), s); }                              \
    s += __shfl_xor(s, 16);                                                        \
    s += __shfl_xor(s, 32);                                                        \
    OUT = s;                                                                       \
    if (lane < 16) {                                                               \
      const float z_ = __expf(-fabsf(s));                                          \
      y[pbase + (it_) * 64 + wvid * 16 + lane] =                                   \
          fmaxf(s, 0.f) + __logf(1.f + z_);   /* softplus */                       \
    } }

  float4 A0, A1, A2, A3, P0, P1, P2, P3;
  float v0, v1, v2, v3, v4, v5, v6, v7;   // named: no runtime-indexed array (rule #20)

  LDX(A0, A1, A2, A3, 0)
  LDX(P0, P1, P2, P3, 1) CMP(A0, A1, A2, A3, 0, v0)
  LDX(A0, A1, A2, A3, 2) CMP(P0, P1, P2, P3, 1, v1)
  LDX(P0, P1, P2, P3, 3) CMP(A0, A1, A2, A3, 2, v2)
  LDX(A0, A1, A2, A3, 4) CMP(P0, P1, P2, P3, 3, v3)
  LDX(P0, P1, P2, P3, 5) CMP(A0, A1, A2, A3, 4, v4)
  LDX(A0, A1, A2, A3, 6) CMP(P0, P1, P2, P3, 5, v5)
  LDX(P0, P1, P2, P3, 7) CMP(A0, A1, A2, A3, 6, v6)
  CMP(P0, P1, P2, P3, 7, v7)
#undef LDX
#undef CMP
#undef PKSPLIT

  // values valid (unique) only in lanes<16; lanes>=16 hold duplicates -> mask them.
  const bool holder = (lane < 16);

  // ---- block stats: max + sum(exp(v - bmax)) over 512 values ----
  float tmax = -INFINITY;
  if (holder)
    tmax = fmaxf(fmaxf(fmaxf(v0, v1), fmaxf(v2, v3)),
                 fmaxf(fmaxf(v4, v5), fmaxf(v6, v7)));
#pragma unroll
  for (int off = 1; off < 64; off <<= 1) tmax = fmaxf(tmax, __shfl_xor(tmax, off));
  if (lane == 0) sbm[wvid] = tmax;
  __syncthreads();
  const float bm = fmaxf(fmaxf(sbm[0], sbm[1]), fmaxf(sbm[2], sbm[3]));
  float tsum = 0.f;
  if (holder)
    tsum = __expf(v0 - bm) + __expf(v1 - bm) + __expf(v2 - bm) + __expf(v3 - bm) +
           __expf(v4 - bm) + __expf(v5 - bm) + __expf(v6 - bm) + __expf(v7 - bm);
#pragma unroll
  for (int off = 1; off < 64; off <<= 1) tsum += __shfl_xor(tsum, off);
  if (lane == 0) sbs[wvid] = tsum;

  // ---- per-wave top-16 of its 128 values (shfl-only; value desc, index asc) ----
  for (int k = 0; k < MP; ++k) {
    float bv = v0; int bt = 0;
    if (v1 > bv) { bv = v1; bt = 1; }
    if (v2 > bv) { bv = v2; bt = 2; }
    if (v3 > bv) { bv = v3; bt = 3; }
    if (v4 > bv) { bv = v4; bt = 4; }
    if (v5 > bv) { bv = v5; bt = 5; }
    if (v6 > bv) { bv = v6; bt = 6; }
    if (v7 > bv) { bv = v7; bt = 7; }
    int bi = holder ? (int)pbase + bt * 64 + wvid * 16 + lane : 0x7fffffff;
    if (!holder) bv = -INFINITY;
#pragma unroll
    for (int off = 1; off < 64; off <<= 1) {
      const float ov = __shfl_xor(bv, off);
      const int   oi = __shfl_xor(bi, off);
      if (ov > bv || (ov == bv && oi < bi)) { bv = ov; bi = oi; }
    }
    if (lane == 0) { cv[wvid][k] = bv; ci[wvid][k] = bi; }
    if (holder) {                           // deflate winner (unique owner lane)
      const int rel = bi - (int)pbase - wvid * 16 - lane;
      if (rel == 0) v0 = -INFINITY;
      else if (rel == 64) v1 = -INFINITY;
      else if (rel == 128) v2 = -INFINITY;
      else if (rel == 192) v3 = -INFINITY;
      else if (rel == 256) v4 = -INFINITY;
      else if (rel == 320) v5 = -INFINITY;
      else if (rel == 384) v6 = -INFINITY;
      else if (rel == 448) v7 = -INFINITY;
    }
  }
  __syncthreads();
  const float bs = sbs[0] + sbs[1] + sbs[2] + sbs[3];

  // ---- wave 0: merge 4x16 -> block top-16, write partials ----
  if (wvid == 0) {
    float mv = cv[lane >> 4][lane & 15];
    int   mi2 = ci[lane >> 4][lane & 15];
    for (int k = 0; k < MP; ++k) {
      float bv = mv; int bi = mi2;
#pragma unroll
      for (int off = 1; off < 64; off <<= 1) {
        const float ov = __shfl_xor(bv, off);
        const int   oi = __shfl_xor(bi, off);
        if (ov > bv || (ov == bv && oi < bi)) { bv = ov; bi = oi; }
      }
      if (lane == 0) { cval[blk * 16 + k] = bv; cidx[blk * 16 + k] = bi; }
      if (mi2 == bi) mv = -INFINITY;
    }
    if (lane == 0) { pmax[blk] = bm; psum[blk] = bs; }
  }
  __syncthreads();              // all block work done
  __threadfence();              // release: drain stores to device scope

  if (t == 0)
    s_old = __hip_atomic_fetch_add(&flags[blk >> 5], 1,
                                   __ATOMIC_ACQ_REL, __HIP_MEMORY_SCOPE_AGENT);
  __syncthreads();
  if (s_old != 31) return;     // not last block of this row

  // ================= FINISHER (exactly one block per row) =================
  __threadfence();             // acquire: see all 32 blocks' partials
  const int brow = blk >> 5;

  if (t < 32) { fm[t] = pmax[brow * 32 + t]; fs[t] = psum[brow * 32 + t]; }
  __syncthreads();
  float m = fm[0];
#pragma unroll
  for (int w = 1; w < 32; ++w) m = fmaxf(m, fm[w]);
  float S = 0.f;
#pragma unroll
  for (int c = 0; c < 32; ++c) S += fs[c] * __expf(fm[c] - m);
  const float inv = __builtin_amdgcn_rcpf(S);

  // ---- y_star over the whole row (float4, coalesced) ----
  float4* __restrict__ rowp = (float4*)(y + (size_t)brow * N);
#pragma unroll
  for (int j = 0; j < 16; ++j) {
    float4 f = rowp[t + 256 * j];
    f.x = fmaf(0.5f, __builtin_amdgcn_rcpf(1.f + __expf(-f.x)), 4.f * __expf(f.x - m) * inv);
    f.y = fmaf(0.5f, __builtin_amdgcn_rcpf(1.f + __expf(-f.y)), 4.f * __expf(f.y - m) * inv);
    f.z = fmaf(0.5f, __builtin_amdgcn_rcpf(1.f + __expf(-f.z)), 4.f * __expf(f.z - m) * inv);
    f.w = fmaf(0.5f, __builtin_amdgcn_rcpf(1.f + __expf(-f.w)), 4.f * __expf(f.w - m) * inv);
    rowp[t + 256 * j] = f;
  }

  // ---- merge 512 candidates -> exact global top-16 ----
  float mv0 = cval[brow * 512 + t];       int mi0 = cidx[brow * 512 + t];
  float mv1 = cval[brow * 512 + 256 + t]; int mi1 = cidx[brow * 512 + 256 + t];
  for (int k = 0; k < MP; ++k) {
    float bv = mv0; int bi = mi0;
    if (mv1 > bv || (mv1 == bv && mi1 < bi)) { bv = mv1; bi = mi1; }
#pragma unroll
    for (int off = 1; off < 64; off <<= 1) {
      const float ov = __shfl_xor(bv, off);
      const int   oi = __shfl_xor(bi, off);
      if (ov > bv || (ov == bv && oi < bi)) { bv = ov; bi = oi; }
    }
    if (lane == 0) { fwv[wvid] = bv; fwi[wvid] = bi; }
    __syncthreads();
    float Bv = fwv[0]; int Bi = fwi[0];
#pragma unroll
    for (int w = 1; w < 4; ++w)
      if (fwv[w] > Bv || (fwv[w] == Bv && fwi[w] < Bi)) { Bv = fwv[w]; Bi = fwi[w]; }
    if (t == 0) { s_val[k] = Bv; s_idx[k] = Bi; }
    if (mi0 == Bi) mv0 = -INFINITY;
    if (mi1 == Bi) mv1 = -INFINITY;
    __syncthreads();
  }

  // ---- lift: (p = t>>4, kd = t&15) ----
  {
    const int p = t >> 4, kd = t & 15;
    const int gidx = s_idx[p];
    const int n = gidx & (N - 1);            // within-row index
    const float salv = s_val[p];
    const float* __restrict__ xr = x + ((size_t)brow * N + n) * DIM;
    float a = b_lift[kd];
#pragma unroll 8
    for (int d = 0; d < DIM; ++d)
      a = fmaf((xr[d] - mu[d]) * __builtin_amdgcn_rcpf(sigma[d]), W_lift[d * KD + kd], a);
    a = fmaf((salv - mu[64]) * __builtin_amdgcn_rcpf(sigma[64]), W_lift[64 * KD + kd], a);
    a = fmaf(((float)n * (1.f / (float)N) - mu[65]) * __builtin_amdgcn_rcpf(sigma[65]),
             W_lift[65 * KD + kd], a);
    lifted[p][kd] = a;
  }
  __syncthreads();

  // ---- project: 16 points x 512 dims; thread t does float2 of each point ----
  const float2* __restrict__ Wp2 = (const float2*)W_proj;
  const float2 bp = ((const float2*)b_proj)[t];
#pragma unroll 1
  for (int p2 = 0; p2 < MP; ++p2) {
    float2 o = bp;
#pragma unroll
    for (int c = 0; c < KD; ++c) {
      const float2 w = Wp2[c * 256 + t];
      o.x = fmaf(lifted[p2][c], w.x, o.x);
      o.y = fmaf(lifted[p2][c], w.y, o.y);
    }
    ((float2*)(tokens + ((size_t)brow * MP + p2) * DM))[t] = o;
  }
}

extern "C" void kernel_launch(void* const* d_in, const int* in_sizes, int n_in,
                              void* d_out, int out_size, void* d_ws, size_t ws_size,
                              hipStream_t stream) {
  const float* x      = (const float*)d_in[0];
  const float* W1     = (const float*)d_in[1];
  const float* b1     = (const float*)d_in[2];
  // d_in[3] = w_e (unused by the reference outputs)
  const float* w_s    = (const float*)d_in[4];
  const float* W_lift = (const float*)d_in[5];
  const float* b_lift = (const float*)d_in[6];
  const float* W_proj = (const float*)d_in[7];
  const float* b_proj = (const float*)d_in[8];
  const float* mu     = (const float*)d_in[9];
  const float* sigma  = (const float*)d_in[10];

  float* tokens = (float*)d_out;                       // [B, MP, DM]
  float* ystar  = (float*)d_out + (size_t)B * MP * DM; // [B, N]

  // workspace: flags[32] | pmax[1024] | psum[1024] | cval[16384] | cidx[16384]
  int*   flags = (int*)d_ws;
  float* pmax  = (float*)d_ws + 32;
  float* psum  = pmax + 1024;
  float* cval  = psum + 1024;
  int*   cidx  = (int*)(cval + 16384);

  (void)hipMemsetAsync(flags, 0, 32 * sizeof(int), stream);   // per-call reset (capture-safe)
  k_all<<<GRID_SAL, 256, 0, stream>>>(x, W1, b1, w_s, ystar, tokens,
                                      W_lift, b_lift, W_proj, b_proj, mu, sigma,
                                      flags, pmax, psum, cval, cidx);
}

// Round 20
// 88.748 us; speedup vs baseline: 2.6190x; 2.6190x over previous
//
#include <hip/hip_runtime.h>
#include <math.h>

#define B 32
#define N 16384
#define DIM 64
#define HID 64
#define KD 16
#define DM 512
#define MP 16

#define GRID_SAL 1024   // 4 blocks/CU; 512 contiguous points per block (32 blocks/row)

typedef __attribute__((ext_vector_type(8))) _Float16 f16x8;
typedef __attribute__((ext_vector_type(2))) __fp16 fph2;   // cvt_pkrtz return type
typedef __attribute__((ext_vector_type(4))) float f32x4;

// tanh via exp + RAW v_rcp (no -ffast-math: '/' would emit the IEEE div sequence).
__device__ __forceinline__ float fast_tanh(float a) {
  const float e = __expf(2.f * a);
  return 1.f - 2.f * __builtin_amdgcn_rcpf(e + 1.f);
}

// ---------- Kernel 1: saliency + per-block softmax partials + per-block top-16 ----------
// All from register-resident values; no sal re-read, no cross-block sync.
__global__ __launch_bounds__(256) void k_salx(
    const float* __restrict__ x, const float* __restrict__ W1,
    const float* __restrict__ b1, const float* __restrict__ w_s,
    float* __restrict__ y, float* __restrict__ pmax, float* __restrict__ psum,
    float* __restrict__ cval, int* __restrict__ cidx) {
  const int t = threadIdx.x;
  const int lane = t & 63, wvid = t >> 6;
  const int c16 = lane & 15, kq = lane >> 4;
  const int blk = blockIdx.x;
  const size_t pbase = (size_t)blk * 512;     // 512 contiguous points, one batch row

  __shared__ __align__(16) _Float16 lWh[64 * 72];
  __shared__ __align__(16) _Float16 lWl[64 * 72];
  __shared__ __align__(16) float lws[64], lb1[64];
  __shared__ float cv[4][16];  __shared__ int ci[4][16];   // per-wave top16
  __shared__ float sbm[4], sbs[4];

#pragma unroll
  for (int j = 0; j < 16; ++j) {
    const int i = t + 256 * j;
    const int k = i >> 6, col = i & 63;
    const float v = W1[i];
    const _Float16 h = (_Float16)v;
    lWh[col * 72 + k] = h;
    lWl[col * 72 + k] = (_Float16)(v - (float)h);
  }
  if (t < 64) { lws[t] = w_s[t]; lb1[t] = b1[t]; }
  __syncthreads();

  f16x8 WH[8], WL[8];
#pragma unroll
  for (int ct = 0; ct < 4; ++ct)
#pragma unroll
    for (int kc = 0; kc < 2; ++kc) {
      const int off = (ct * 16 + c16) * 72 + kc * 32 + kq * 8;
      WH[ct * 2 + kc] = *(const f16x8*)(lWh + off);
      WL[ct * 2 + kc] = *(const f16x8*)(lWl + off);
    }

#define PKSPLIT(va, vb, HW, LW) {                                                  \
    const fph2 h_ = __builtin_amdgcn_cvt_pkrtz((va), (vb));                        \
    const fph2 l_ = __builtin_amdgcn_cvt_pkrtz((va) - (float)h_[0],                \
                                               (vb) - (float)h_[1]);               \
    HW = __builtin_bit_cast(unsigned, h_);                                         \
    LW = __builtin_bit_cast(unsigned, l_); }

#define LDX(b0, b1_, b2, b3, it_) {                                                \
    const size_t row_ = pbase + (it_) * 64 + wvid * 16 + c16;                      \
    const float* __restrict__ p_ = x + row_ * DIM + kq * 8;                        \
    b0 = *(const float4*)(p_);       b1_ = *(const float4*)(p_ + 4);               \
    b2 = *(const float4*)(p_ + 32);  b3 = *(const float4*)(p_ + 36); }

// computes sp = softplus(s) in ALL lanes; OUT := sp; lanes<16 write y.
#define CMP(b0, b1_, b2, b3, it_, OUT) {                                           \
    f32x4 a0 = (f32x4)0.f, a1 = (f32x4)0.f, a2 = (f32x4)0.f, a3 = (f32x4)0.f;      \
    { uint4 H, L;                                                                  \
      PKSPLIT(b0.x, b0.y, H.x, L.x); PKSPLIT(b0.z, b0.w, H.y, L.y);                \
      PKSPLIT(b1_.x, b1_.y, H.z, L.z); PKSPLIT(b1_.z, b1_.w, H.w, L.w);            \
      const f16x8 bh = __builtin_bit_cast(f16x8, H);                               \
      const f16x8 bl = __builtin_bit_cast(f16x8, L);                               \
      a0 = __builtin_amdgcn_mfma_f32_16x16x32_f16(WH[0], bh, a0, 0, 0, 0);         \
      a1 = __builtin_amdgcn_mfma_f32_16x16x32_f16(WH[2], bh, a1, 0, 0, 0);         \
      a2 = __builtin_amdgcn_mfma_f32_16x16x32_f16(WH[4], bh, a2, 0, 0, 0);         \
      a3 = __builtin_amdgcn_mfma_f32_16x16x32_f16(WH[6], bh, a3, 0, 0, 0);         \
      a0 = __builtin_amdgcn_mfma_f32_16x16x32_f16(WL[0], bh, a0, 0, 0, 0);         \
      a1 = __builtin_amdgcn_mfma_f32_16x16x32_f16(WL[2], bh, a1, 0, 0, 0);         \
      a2 = __builtin_amdgcn_mfma_f32_16x16x32_f16(WL[4], bh, a2, 0, 0, 0);         \
      a3 = __builtin_amdgcn_mfma_f32_16x16x32_f16(WL[6], bh, a3, 0, 0, 0);         \
      a0 = __builtin_amdgcn_mfma_f32_16x16x32_f16(WH[0], bl, a0, 0, 0, 0);         \
      a1 = __builtin_amdgcn_mfma_f32_16x16x32_f16(WH[2], bl, a1, 0, 0, 0);         \
      a2 = __builtin_amdgcn_mfma_f32_16x16x32_f16(WH[4], bl, a2, 0, 0, 0);         \
      a3 = __builtin_amdgcn_mfma_f32_16x16x32_f16(WH[6], bl, a3, 0, 0, 0); }       \
    { uint4 H, L;                                                                  \
      PKSPLIT(b2.x, b2.y, H.x, L.x); PKSPLIT(b2.z, b2.w, H.y, L.y);                \
      PKSPLIT(b3.x, b3.y, H.z, L.z); PKSPLIT(b3.z, b3.w, H.w, L.w);                \
      const f16x8 bh = __builtin_bit_cast(f16x8, H);                               \
      const f16x8 bl = __builtin_bit_cast(f16x8, L);                               \
      a0 = __builtin_amdgcn_mfma_f32_16x16x32_f16(WH[1], bh, a0, 0, 0, 0);         \
      a1 = __builtin_amdgcn_mfma_f32_16x16x32_f16(WH[3], bh, a1, 0, 0, 0);         \
      a2 = __builtin_amdgcn_mfma_f32_16x16x32_f16(WH[5], bh, a2, 0, 0, 0);         \
      a3 = __builtin_amdgcn_mfma_f32_16x16x32_f16(WH[7], bh, a3, 0, 0, 0);         \
      a0 = __builtin_amdgcn_mfma_f32_16x16x32_f16(WL[1], bh, a0, 0, 0, 0);         \
      a1 = __builtin_amdgcn_mfma_f32_16x16x32_f16(WL[3], bh, a1, 0, 0, 0);         \
      a2 = __builtin_amdgcn_mfma_f32_16x16x32_f16(WL[5], bh, a2, 0, 0, 0);         \
      a3 = __builtin_amdgcn_mfma_f32_16x16x32_f16(WL[7], bh, a3, 0, 0, 0);         \
      a0 = __builtin_amdgcn_mfma_f32_16x16x32_f16(WH[1], bl, a0, 0, 0, 0);         \
      a1 = __builtin_amdgcn_mfma_f32_16x16x32_f16(WH[3], bl, a1, 0, 0, 0);         \
      a2 = __builtin_amdgcn_mfma_f32_16x16x32_f16(WH[5], bl, a2, 0, 0, 0);         \
      a3 = __builtin_amdgcn_mfma_f32_16x16x32_f16(WH[7], bl, a3, 0, 0, 0); }       \
    float s = 0.f;                                                                 \
    { const f32x4 wv = *(const f32x4*)(lws + kq * 4);                              \
      const f32x4 bv = *(const f32x4*)(lb1 + kq * 4);                              \
      s = fmaf(wv[0], fast_tanh(a0[0] + bv[0]), s);                                \
      s = fmaf(wv[1], fast_tanh(a0[1] + bv[1]), s);                                \
      s = fmaf(wv[2], fast_tanh(a0[2] + bv[2]), s);                                \
      s = fmaf(wv[3], fast_tanh(a0[3] + bv[3]), s); }                              \
    { const f32x4 wv = *(const f32x4*)(lws + 16 + kq * 4);                         \
      const f32x4 bv = *(const f32x4*)(lb1 + 16 + kq * 4);                         \
      s = fmaf(wv[0], fast_tanh(a1[0] + bv[0]), s);                                \
      s = fmaf(wv[1], fast_tanh(a1[1] + bv[1]), s);                                \
      s = fmaf(wv[2], fast_tanh(a1[2] + bv[2]), s);                                \
      s = fmaf(wv[3], fast_tanh(a1[3] + bv[3]), s); }                              \
    { const f32x4 wv = *(const f32x4*)(lws + 32 + kq * 4);                         \
      const f32x4 bv = *(const f32x4*)(lb1 + 32 + kq * 4);                         \
      s = fmaf(wv[0], fast_tanh(a2[0] + bv[0]), s);                                \
      s = fmaf(wv[1], fast_tanh(a2[1] + bv[1]), s);                                \
      s = fmaf(wv[2], fast_tanh(a2[2] + bv[2]), s);                                \
      s = fmaf(wv[3], fast_tanh(a2[3] + bv[3]), s); }                              \
    { const f32x4 wv = *(const f32x4*)(lws + 48 + kq * 4);                         \
      const f32x4 bv = *(const f32x4*)(lb1 + 48 + kq * 4);                         \
      s = fmaf(wv[0], fast_tanh(a3[0] + bv[0]), s);                                \
      s = fmaf(wv[1], fast_tanh(a3[1] + bv[1]), s);                                \
      s = fmaf(wv[2], fast_tanh(a3[2] + bv[2]), s);                                \
      s = fmaf(wv[3], fast_tanh(a3[3] + bv[3]), s); }                              \
    s += __shfl_xor(s, 16);                                                        \
    s += __shfl_xor(s, 32);                                                        \
    const float sp_ = fmaxf(s, 0.f) + __logf(1.f + __expf(-fabsf(s)));             \
    OUT = sp_;                                                                     \
    if (lane < 16)                                                                 \
      y[pbase + (it_) * 64 + wvid * 16 + lane] = sp_;                              \
  }

  float4 A0, A1, A2, A3, P0, P1, P2, P3;
  float v0, v1, v2, v3, v4, v5, v6, v7;   // named: no runtime-indexed array (rule #20)

  LDX(A0, A1, A2, A3, 0)
  LDX(P0, P1, P2, P3, 1) CMP(A0, A1, A2, A3, 0, v0)
  LDX(A0, A1, A2, A3, 2) CMP(P0, P1, P2, P3, 1, v1)
  LDX(P0, P1, P2, P3, 3) CMP(A0, A1, A2, A3, 2, v2)
  LDX(A0, A1, A2, A3, 4) CMP(P0, P1, P2, P3, 3, v3)
  LDX(P0, P1, P2, P3, 5) CMP(A0, A1, A2, A3, 4, v4)
  LDX(A0, A1, A2, A3, 6) CMP(P0, P1, P2, P3, 5, v5)
  LDX(P0, P1, P2, P3, 7) CMP(A0, A1, A2, A3, 6, v6)
  CMP(P0, P1, P2, P3, 7, v7)
#undef LDX
#undef CMP
#undef PKSPLIT

  // values unique only in lanes<16 (all lanes hold copies) -> mask others.
  const bool holder = (lane < 16);

  // ---- block stats over the 512 saliency (softplus) values ----
  float tmax = -INFINITY;
  if (holder)
    tmax = fmaxf(fmaxf(fmaxf(v0, v1), fmaxf(v2, v3)),
                 fmaxf(fmaxf(v4, v5), fmaxf(v6, v7)));
#pragma unroll
  for (int off = 1; off < 64; off <<= 1) tmax = fmaxf(tmax, __shfl_xor(tmax, off));
  if (lane == 0) sbm[wvid] = tmax;
  __syncthreads();
  const float bm = fmaxf(fmaxf(sbm[0], sbm[1]), fmaxf(sbm[2], sbm[3]));
  float tsum = 0.f;
  if (holder)
    tsum = __expf(v0 - bm) + __expf(v1 - bm) + __expf(v2 - bm) + __expf(v3 - bm) +
           __expf(v4 - bm) + __expf(v5 - bm) + __expf(v6 - bm) + __expf(v7 - bm);
#pragma unroll
  for (int off = 1; off < 64; off <<= 1) tsum += __shfl_xor(tsum, off);
  if (lane == 0) sbs[wvid] = tsum;

  // ---- per-wave top-16 of its 128 values (value desc, index asc; global flat idx) ----
  for (int k = 0; k < MP; ++k) {
    float bv = v0; int bt = 0;
    if (v1 > bv) { bv = v1; bt = 1; }
    if (v2 > bv) { bv = v2; bt = 2; }
    if (v3 > bv) { bv = v3; bt = 3; }
    if (v4 > bv) { bv = v4; bt = 4; }
    if (v5 > bv) { bv = v5; bt = 5; }
    if (v6 > bv) { bv = v6; bt = 6; }
    if (v7 > bv) { bv = v7; bt = 7; }
    int bi = holder ? (int)pbase + bt * 64 + wvid * 16 + lane : 0x7fffffff;
    if (!holder) bv = -INFINITY;
#pragma unroll
    for (int off = 1; off < 64; off <<= 1) {
      const float ov = __shfl_xor(bv, off);
      const int   oi = __shfl_xor(bi, off);
      if (ov > bv || (ov == bv && oi < bi)) { bv = ov; bi = oi; }
    }
    if (lane == 0) { cv[wvid][k] = bv; ci[wvid][k] = bi; }
    if (holder) {                           // deflate winner (unique owner lane)
      const int rel = bi - (int)pbase - wvid * 16 - lane;
      if (rel == 0) v0 = -INFINITY;
      else if (rel == 64) v1 = -INFINITY;
      else if (rel == 128) v2 = -INFINITY;
      else if (rel == 192) v3 = -INFINITY;
      else if (rel == 256) v4 = -INFINITY;
      else if (rel == 320) v5 = -INFINITY;
      else if (rel == 384) v6 = -INFINITY;
      else if (rel == 448) v7 = -INFINITY;
    }
  }
  __syncthreads();
  const float bs = sbs[0] + sbs[1] + sbs[2] + sbs[3];

  // ---- wave 0: merge 4x16 -> block top-16; write partials ----
  if (wvid == 0) {
    float mv = cv[lane >> 4][lane & 15];
    int   mi2 = ci[lane >> 4][lane & 15];
    for (int k = 0; k < MP; ++k) {
      float bv = mv; int bi = mi2;
#pragma unroll
      for (int off = 1; off < 64; off <<= 1) {
        const float ov = __shfl_xor(bv, off);
        const int   oi = __shfl_xor(bi, off);
        if (ov > bv || (ov == bv && oi < bi)) { bv = ov; bi = oi; }
      }
      if (lane == 0) { cval[blk * 16 + k] = bv; cidx[blk * 16 + k] = bi; }
      if (mi2 == bi) mv = -INFINITY;
    }
    if (lane == 0) { pmax[blk] = bm; psum[blk] = bs; }
  }
}

// ---------- Kernel 2: heterogeneous final (r14 pattern):
// blocks 0..31 = merge 512 candidates + lift + project; blocks 32..2079 = y_star ----------
__global__ __launch_bounds__(256) void k_final(
    float* __restrict__ y, const float* __restrict__ pmax, const float* __restrict__ psum,
    const float* __restrict__ cval, const int* __restrict__ cidx,
    const float* __restrict__ x,
    const float* __restrict__ W_lift, const float* __restrict__ b_lift,
    const float* __restrict__ W_proj, const float* __restrict__ b_proj,
    const float* __restrict__ mu, const float* __restrict__ sigma,
    float* __restrict__ tokens) {
  const int t = threadIdx.x;

  if (blockIdx.x >= 32) {
    // ---------------- y_star role ----------------
    const int bid = blockIdx.x - 32;              // 0..2047
    const int b = bid >> 6;                       // 64 blocks per row
    const int gi = bid * 256 + t;
    float mx = pmax[b * 32];
#pragma unroll
    for (int c = 1; c < 32; ++c) mx = fmaxf(mx, pmax[b * 32 + c]);
    float S = 0.f;
#pragma unroll
    for (int c = 0; c < 32; ++c) S += psum[b * 32 + c] * __expf(pmax[b * 32 + c] - mx);
    const float inv = __builtin_amdgcn_rcpf(S);
    const float v = y[gi];
    const float sig = __builtin_amdgcn_rcpf(1.f + __expf(-v));
    y[gi] = fmaf(0.5f, sig, 4.f * __expf(v - mx) * inv);
    return;
  }

  // ---------------- merge + lift + project role ----------------
  __shared__ float fwv[4], s_val[MP];
  __shared__ int fwi[4], s_idx[MP];
  __shared__ float lifted[MP][KD + 1];
  const int b = blockIdx.x, lane = t & 63, wvid = t >> 6;

  // 512 candidates, 2 per thread
  float mv0 = cval[b * 512 + t];       int mi0 = cidx[b * 512 + t];
  float mv1 = cval[b * 512 + 256 + t]; int mi1 = cidx[b * 512 + 256 + t];
  for (int k = 0; k < MP; ++k) {
    float bv = mv0; int bi = mi0;
    if (mv1 > bv || (mv1 == bv && mi1 < bi)) { bv = mv1; bi = mi1; }
#pragma unroll
    for (int off = 1; off < 64; off <<= 1) {
      const float ov = __shfl_xor(bv, off);
      const int   oi = __shfl_xor(bi, off);
      if (ov > bv || (ov == bv && oi < bi)) { bv = ov; bi = oi; }
    }
    if (lane == 0) { fwv[wvid] = bv; fwi[wvid] = bi; }
    __syncthreads();
    float Bv = fwv[0]; int Bi = fwi[0];
#pragma unroll
    for (int w = 1; w < 4; ++w)
      if (fwv[w] > Bv || (fwv[w] == Bv && fwi[w] < Bi)) { Bv = fwv[w]; Bi = fwi[w]; }
    if (t == 0) { s_val[k] = Bv; s_idx[k] = Bi; }
    if (mi0 == Bi) mv0 = -INFINITY;
    if (mi1 == Bi) mv1 = -INFINITY;
    __syncthreads();
  }

  // ---- lift: (p = t>>4, kd = t&15) ----
  {
    const int p = t >> 4, kd = t & 15;
    const int gidx = s_idx[p];
    const int n = gidx & (N - 1);            // within-row index
    const float salv = s_val[p];             // saliency (softplus) of the point
    const float* __restrict__ xr = x + ((size_t)b * N + n) * DIM;
    float a = b_lift[kd];
#pragma unroll 8
    for (int d = 0; d < DIM; ++d)
      a = fmaf((xr[d] - mu[d]) * __builtin_amdgcn_rcpf(sigma[d]), W_lift[d * KD + kd], a);
    a = fmaf((salv - mu[64]) * __builtin_amdgcn_rcpf(sigma[64]), W_lift[64 * KD + kd], a);
    a = fmaf(((float)n * (1.f / (float)N) - mu[65]) * __builtin_amdgcn_rcpf(sigma[65]),
             W_lift[65 * KD + kd], a);
    lifted[p][kd] = a;
  }
  __syncthreads();

  // ---- project: 16 points x 512 dims; thread t does float2 of each point ----
  const float2* __restrict__ Wp2 = (const float2*)W_proj;
  const float2 bp = ((const float2*)b_proj)[t];
#pragma unroll 1
  for (int p2 = 0; p2 < MP; ++p2) {
    float2 o = bp;
#pragma unroll
    for (int c = 0; c < KD; ++c) {
      const float2 w = Wp2[c * 256 + t];
      o.x = fmaf(lifted[p2][c], w.x, o.x);
      o.y = fmaf(lifted[p2][c], w.y, o.y);
    }
    ((float2*)(tokens + ((size_t)b * MP + p2) * DM))[t] = o;
  }
}

extern "C" void kernel_launch(void* const* d_in, const int* in_sizes, int n_in,
                              void* d_out, int out_size, void* d_ws, size_t ws_size,
                              hipStream_t stream) {
  const float* x      = (const float*)d_in[0];
  const float* W1     = (const float*)d_in[1];
  const float* b1     = (const float*)d_in[2];
  // d_in[3] = w_e (unused by the reference outputs)
  const float* w_s    = (const float*)d_in[4];
  const float* W_lift = (const float*)d_in[5];
  const float* b_lift = (const float*)d_in[6];
  const float* W_proj = (const float*)d_in[7];
  const float* b_proj = (const float*)d_in[8];
  const float* mu     = (const float*)d_in[9];
  const float* sigma  = (const float*)d_in[10];

  float* tokens = (float*)d_out;                       // [B, MP, DM]
  float* ystar  = (float*)d_out + (size_t)B * MP * DM; // [B, N]

  // workspace: pmax[1024] | psum[1024] | cval[16384] | cidx[16384]
  float* pmax  = (float*)d_ws;
  float* psum  = pmax + 1024;
  float* cval  = psum + 1024;
  int*   cidx  = (int*)(cval + 16384);

  k_salx<<<GRID_SAL, 256, 0, stream>>>(x, W1, b1, w_s, ystar,
                                       pmax, psum, cval, cidx);
  k_final<<<2048 + 32, 256, 0, stream>>>(ystar, pmax, psum, cval, cidx, x,
                                         W_lift, b_lift, W_proj, b_proj,
                                         mu, sigma, tokens);
}

// Round 21
// 69.494 us; speedup vs baseline: 3.3446x; 1.2771x over previous
//
#include <hip/hip_runtime.h>
#include <math.h>

#define B 32
#define N 16384
#define DIM 64
#define HID 64
#define KD 16
#define DM 512
#define MP 16

#define GRID_SAL 1024   // 4 blocks/CU (r13: 2048 hurts)
#define ITERS 8         // 1024 * 8 * 64 rows = 524288 = B*N

typedef __attribute__((ext_vector_type(8))) _Float16 f16x8;
typedef __attribute__((ext_vector_type(2))) __fp16 fph2;   // cvt_pkrtz return type
typedef __attribute__((ext_vector_type(4))) float f32x4;

// tanh via exp + RAW v_rcp (no -ffast-math: '/' would emit the IEEE div sequence).
__device__ __forceinline__ float fast_tanh(float a) {
  const float e = __expf(2.f * a);
  return 1.f - 2.f * __builtin_amdgcn_rcpf(e + 1.f);
}

// ---------- Kernel 1: saliency; W1 converted in-block (LDS) then held in registers ----------
__global__ __launch_bounds__(256) void k_saliency(
    const float* __restrict__ x, const float* __restrict__ W1,
    const float* __restrict__ b1, const float* __restrict__ w_s,
    float* __restrict__ sal) {
  const int t = threadIdx.x;
  const int lane = t & 63, wid = t >> 6;
  const int c16 = lane & 15, kq = lane >> 4;

  // ---- prologue: W1[k][col] -> LDS [col][72-padded k] fp16 hi/lo, then fragments ----
  __shared__ __align__(16) _Float16 lWh[64 * 72];   // 9216 B
  __shared__ __align__(16) _Float16 lWl[64 * 72];   // 9216 B
#pragma unroll
  for (int j = 0; j < 16; ++j) {
    const int i = t + 256 * j;            // coalesced read of 4096 floats
    const int k = i >> 6, col = i & 63;
    const float v = W1[i];
    const _Float16 h = (_Float16)v;
    lWh[col * 72 + k] = h;
    lWl[col * 72 + k] = (_Float16)(v - (float)h);
  }
  __syncthreads();

  f16x8 WH[8], WL[8];                     // tile-invariant, 64 VGPR
#pragma unroll
  for (int ct = 0; ct < 4; ++ct)
#pragma unroll
    for (int kc = 0; kc < 2; ++kc) {
      const int off = (ct * 16 + c16) * 72 + kc * 32 + kq * 8;   // byte off %16 == 0
      WH[ct * 2 + kc] = *(const f16x8*)(lWh + off);
      WL[ct * 2 + kc] = *(const f16x8*)(lWl + off);
    }

#define PKSPLIT(va, vb, HW, LW) {                                                  \
    const fph2 h_ = __builtin_amdgcn_cvt_pkrtz((va), (vb));                        \
    const fph2 l_ = __builtin_amdgcn_cvt_pkrtz((va) - (float)h_[0],                \
                                               (vb) - (float)h_[1]);               \
    HW = __builtin_bit_cast(unsigned, h_);                                         \
    LW = __builtin_bit_cast(unsigned, l_); }

#define SAL_LOADS(b0, b1_, b2, b3, it_) {                                          \
    const size_t row_ = ((size_t)(it_) * GRID_SAL + blockIdx.x) * 64 + wid * 16 + c16; \
    const float* __restrict__ p_ = x + row_ * DIM + kq * 8;                        \
    b0 = *(const float4*)(p_);       b1_ = *(const float4*)(p_ + 4);               \
    b2 = *(const float4*)(p_ + 32);  b3 = *(const float4*)(p_ + 36); }

#define SAL_COMPUTE(b0, b1_, b2, b3, it_) {                                        \
    f32x4 a0 = (f32x4)0.f, a1 = (f32x4)0.f, a2 = (f32x4)0.f, a3 = (f32x4)0.f;      \
    { /* kc = 0 */                                                                 \
      uint4 H, L;                                                                  \
      PKSPLIT(b0.x, b0.y, H.x, L.x); PKSPLIT(b0.z, b0.w, H.y, L.y);                \
      PKSPLIT(b1_.x, b1_.y, H.z, L.z); PKSPLIT(b1_.z, b1_.w, H.w, L.w);            \
      const f16x8 bh = __builtin_bit_cast(f16x8, H);                               \
      const f16x8 bl = __builtin_bit_cast(f16x8, L);                               \
      a0 = __builtin_amdgcn_mfma_f32_16x16x32_f16(WH[0], bh, a0, 0, 0, 0);         \
      a1 = __builtin_amdgcn_mfma_f32_16x16x32_f16(WH[2], bh, a1, 0, 0, 0);         \
      a2 = __builtin_amdgcn_mfma_f32_16x16x32_f16(WH[4], bh, a2, 0, 0, 0);         \
      a3 = __builtin_amdgcn_mfma_f32_16x16x32_f16(WH[6], bh, a3, 0, 0, 0);         \
      a0 = __builtin_amdgcn_mfma_f32_16x16x32_f16(WL[0], bh, a0, 0, 0, 0);         \
      a1 = __builtin_amdgcn_mfma_f32_16x16x32_f16(WL[2], bh, a1, 0, 0, 0);         \
      a2 = __builtin_amdgcn_mfma_f32_16x16x32_f16(WL[4], bh, a2, 0, 0, 0);         \
      a3 = __builtin_amdgcn_mfma_f32_16x16x32_f16(WL[6], bh, a3, 0, 0, 0);         \
      a0 = __builtin_amdgcn_mfma_f32_16x16x32_f16(WH[0], bl, a0, 0, 0, 0);         \
      a1 = __builtin_amdgcn_mfma_f32_16x16x32_f16(WH[2], bl, a1, 0, 0, 0);         \
      a2 = __builtin_amdgcn_mfma_f32_16x16x32_f16(WH[4], bl, a2, 0, 0, 0);         \
      a3 = __builtin_amdgcn_mfma_f32_16x16x32_f16(WH[6], bl, a3, 0, 0, 0);         \
    }                                                                              \
    { /* kc = 1 */                                                                 \
      uint4 H, L;                                                                  \
      PKSPLIT(b2.x, b2.y, H.x, L.x); PKSPLIT(b2.z, b2.w, H.y, L.y);                \
      PKSPLIT(b3.x, b3.y, H.z, L.z); PKSPLIT(b3.z, b3.w, H.w, L.w);                \
      const f16x8 bh = __builtin_bit_cast(f16x8, H);                               \
      const f16x8 bl = __builtin_bit_cast(f16x8, L);                               \
      a0 = __builtin_amdgcn_mfma_f32_16x16x32_f16(WH[1], bh, a0, 0, 0, 0);         \
      a1 = __builtin_amdgcn_mfma_f32_16x16x32_f16(WH[3], bh, a1, 0, 0, 0);         \
      a2 = __builtin_amdgcn_mfma_f32_16x16x32_f16(WH[5], bh, a2, 0, 0, 0);         \
      a3 = __builtin_amdgcn_mfma_f32_16x16x32_f16(WH[7], bh, a3, 0, 0, 0);         \
      a0 = __builtin_amdgcn_mfma_f32_16x16x32_f16(WL[1], bh, a0, 0, 0, 0);         \
      a1 = __builtin_amdgcn_mfma_f32_16x16x32_f16(WL[3], bh, a1, 0, 0, 0);         \
      a2 = __builtin_amdgcn_mfma_f32_16x16x32_f16(WL[5], bh, a2, 0, 0, 0);         \
      a3 = __builtin_amdgcn_mfma_f32_16x16x32_f16(WL[7], bh, a3, 0, 0, 0);         \
      a0 = __builtin_amdgcn_mfma_f32_16x16x32_f16(WH[1], bl, a0, 0, 0, 0);         \
      a1 = __builtin_amdgcn_mfma_f32_16x16x32_f16(WH[3], bl, a1, 0, 0, 0);         \
      a2 = __builtin_amdgcn_mfma_f32_16x16x32_f16(WH[5], bl, a2, 0, 0, 0);         \
      a3 = __builtin_amdgcn_mfma_f32_16x16x32_f16(WH[7], bl, a3, 0, 0, 0);         \
    }                                                                              \
    float s = 0.f;                                                                 \
    { const f32x4 wv = *(const f32x4*)(w_s + kq * 4);                              \
      const f32x4 bv = *(const f32x4*)(b1 + kq * 4);                               \
      s = fmaf(wv[0], fast_tanh(a0[0] + bv[0]), s);                                \
      s = fmaf(wv[1], fast_tanh(a0[1] + bv[1]), s);                                \
      s = fmaf(wv[2], fast_tanh(a0[2] + bv[2]), s);                                \
      s = fmaf(wv[3], fast_tanh(a0[3] + bv[3]), s); }                              \
    { const f32x4 wv = *(const f32x4*)(w_s + 16 + kq * 4);                         \
      const f32x4 bv = *(const f32x4*)(b1 + 16 + kq * 4);                          \
      s = fmaf(wv[0], fast_tanh(a1[0] + bv[0]), s);                                \
      s = fmaf(wv[1], fast_tanh(a1[1] + bv[1]), s);                                \
      s = fmaf(wv[2], fast_tanh(a1[2] + bv[2]), s);                                \
      s = fmaf(wv[3], fast_tanh(a1[3] + bv[3]), s); }                              \
    { const f32x4 wv = *(const f32x4*)(w_s + 32 + kq * 4);                         \
      const f32x4 bv = *(const f32x4*)(b1 + 32 + kq * 4);                          \
      s = fmaf(wv[0], fast_tanh(a2[0] + bv[0]), s);                                \
      s = fmaf(wv[1], fast_tanh(a2[1] + bv[1]), s);                                \
      s = fmaf(wv[2], fast_tanh(a2[2] + bv[2]), s);                                \
      s = fmaf(wv[3], fast_tanh(a2[3] + bv[3]), s); }                              \
    { const f32x4 wv = *(const f32x4*)(w_s + 48 + kq * 4);                         \
      const f32x4 bv = *(const f32x4*)(b1 + 48 + kq * 4);                          \
      s = fmaf(wv[0], fast_tanh(a3[0] + bv[0]), s);                                \
      s = fmaf(wv[1], fast_tanh(a3[1] + bv[1]), s);                                \
      s = fmaf(wv[2], fast_tanh(a3[2] + bv[2]), s);                                \
      s = fmaf(wv[3], fast_tanh(a3[3] + bv[3]), s); }                              \
    s += __shfl_xor(s, 16);                                                        \
    s += __shfl_xor(s, 32);                                                        \
    if (lane < 16) {                                                               \
      const size_t sr_ = ((size_t)(it_) * GRID_SAL + blockIdx.x) * 64 + wid * 16 + lane; \
      const float z_ = __expf(-fabsf(s));                                          \
      sal[sr_] = fmaxf(s, 0.f) + __logf(1.f + z_);   /* softplus, no libm */       \
    } }

  float4 pA0, pA1, pA2, pA3;   // ping buffer
  float4 pB0, pB1, pB2, pB3;   // pong buffer

  SAL_LOADS(pA0, pA1, pA2, pA3, 0);
#pragma unroll 1
  for (int it2 = 0; it2 < ITERS; it2 += 2) {
    SAL_LOADS(pB0, pB1, pB2, pB3, it2 + 1);       // prefetch odd tile
    SAL_COMPUTE(pA0, pA1, pA2, pA3, it2);         // compute even tile
    if (it2 + 2 < ITERS) SAL_LOADS(pA0, pA1, pA2, pA3, it2 + 2);
    SAL_COMPUTE(pB0, pB1, pB2, pB3, it2 + 1);     // compute odd tile
  }
#undef SAL_LOADS
#undef SAL_COMPUTE
#undef PKSPLIT
}

// ---------- Kernel 2: per-chunk (2048 elems) online-softmax partials + top-16 ----------
// Indices stored WITHIN-ROW (0..N-1): chunk c covers row (c>>3), row-offset (c&7)*2048.
__global__ __launch_bounds__(256) void k_chunk(
    const float* __restrict__ sal, float* __restrict__ cmax, float* __restrict__ csum,
    float* __restrict__ cval, int* __restrict__ cidx) {
  __shared__ float sb[4], ss[4], wv[4];
  __shared__ int wi[4];
  const int t = threadIdx.x, c = blockIdx.x;
  const int rowoff = (c & 7) * 2048;
  const size_t gbase = (size_t)c * 2048;
  float v[8];
#pragma unroll
  for (int j = 0; j < 8; ++j) v[j] = sal[gbase + t + 256 * j];

  float m = v[0];
#pragma unroll
  for (int j = 1; j < 8; ++j) m = fmaxf(m, v[j]);
#pragma unroll
  for (int off = 1; off < 64; off <<= 1) m = fmaxf(m, __shfl_xor(m, off));
  if ((t & 63) == 0) sb[t >> 6] = m;
  __syncthreads();
  m = fmaxf(fmaxf(sb[0], sb[1]), fmaxf(sb[2], sb[3]));

  float se = 0.f;
#pragma unroll
  for (int j = 0; j < 8; ++j) se += __expf(v[j] - m);
#pragma unroll
  for (int off = 1; off < 64; off <<= 1) se += __shfl_xor(se, off);
  if ((t & 63) == 0) ss[t >> 6] = se;
  __syncthreads();
  if (t == 0) { cmax[c] = m; csum[c] = ss[0] + ss[1] + ss[2] + ss[3]; }

  // top-16 of chunk, (value desc, index asc), indices within-row
  for (int k = 0; k < MP; ++k) {
    float bv = v[0]; int bj = 0;
#pragma unroll
    for (int j = 1; j < 8; ++j)
      if (v[j] > bv) { bv = v[j]; bj = j; }
    int bi = rowoff + t + 256 * bj;
#pragma unroll
    for (int off = 1; off < 64; off <<= 1) {
      const float ov = __shfl_xor(bv, off);
      const int   oi = __shfl_xor(bi, off);
      if (ov > bv || (ov == bv && oi < bi)) { bv = ov; bi = oi; }
    }
    if ((t & 63) == 0) { wv[t >> 6] = bv; wi[t >> 6] = bi; }
    __syncthreads();
    float Bv = wv[0]; int Bi = wi[0];
#pragma unroll
    for (int w = 1; w < 4; ++w)
      if (wv[w] > Bv || (wv[w] == Bv && wi[w] < Bi)) { Bv = wv[w]; Bi = wi[w]; }
    if (t == 0) { cval[c * MP + k] = Bv; cidx[c * MP + k] = Bi; }
    const int relidx = Bi - rowoff;
#pragma unroll
    for (int jj = 0; jj < 8; ++jj)
      if (relidx == t + 256 * jj) v[jj] = -INFINITY;
    __syncthreads();
  }
}

// ---------- Kernel 3: heterogeneous final: blocks 0..31 = merge+lift+project; 32..2079 = y_star ----------
__global__ __launch_bounds__(256) void k_final(
    float* __restrict__ y, const float* __restrict__ cmax, const float* __restrict__ csum,
    const float* __restrict__ cval, const int* __restrict__ cidx,
    const float* __restrict__ x,
    const float* __restrict__ W_lift, const float* __restrict__ b_lift,
    const float* __restrict__ W_proj, const float* __restrict__ b_proj,
    const float* __restrict__ mu, const float* __restrict__ sigma,
    float* __restrict__ tokens) {
  const int t = threadIdx.x;

  if (blockIdx.x >= 32) {
    // ---------------- y_star role ----------------
    const int bid = blockIdx.x - 32;              // 0..2047
    const int b = bid >> 6;                       // 64 blocks per row
    const int gi = bid * 256 + t;
    float mx = cmax[b * 8];
#pragma unroll
    for (int c = 1; c < 8; ++c) mx = fmaxf(mx, cmax[b * 8 + c]);
    float S = 0.f;
#pragma unroll
    for (int c = 0; c < 8; ++c) S += csum[b * 8 + c] * __expf(cmax[b * 8 + c] - mx);
    const float inv = __builtin_amdgcn_rcpf(S);
    const float v = y[gi];
    const float sig = __builtin_amdgcn_rcpf(1.f + __expf(-v));
    y[gi] = fmaf(0.5f, sig, 4.f * __expf(v - mx) * inv);
    return;
  }

  // ---------------- merge + lift + project role ----------------
  __shared__ float wv[4];
  __shared__ int wi[4];
  __shared__ float s_val[MP];
  __shared__ int s_idx[MP];
  __shared__ float lifted[MP][KD + 1];
  const int b = blockIdx.x;

  // merge 128 candidates -> global top-16 (value desc, index asc)
  float v = -INFINITY; int i = 0x7fffffff;
  if (t < 128) { v = cval[b * 128 + t]; i = cidx[b * 128 + t]; }
  for (int k = 0; k < MP; ++k) {
    float bv = v; int bi = i;
#pragma unroll
    for (int off = 1; off < 64; off <<= 1) {
      const float ov = __shfl_xor(bv, off);
      const int   oi = __shfl_xor(bi, off);
      if (ov > bv || (ov == bv && oi < bi)) { bv = ov; bi = oi; }
    }
    if ((t & 63) == 0) { wv[t >> 6] = bv; wi[t >> 6] = bi; }
    __syncthreads();
    float Bv = wv[0]; int Bi = wi[0];
#pragma unroll
    for (int w = 1; w < 4; ++w)
      if (wv[w] > Bv || (wv[w] == Bv && wi[w] < Bi)) { Bv = wv[w]; Bi = wi[w]; }
    if (t == 0) { s_val[k] = Bv; s_idx[k] = Bi; }
    if (i == Bi) v = -INFINITY;
    __syncthreads();
  }

  // lift: thread (p = t>>4, kd = t&15) computes lifted[p][kd]; 1/sigma via v_rcp
  const int p = t >> 4, kd = t & 15;
  const int idx = s_idx[p];
  const float salv = s_val[p];
  const float* __restrict__ xr = x + ((size_t)b * N + idx) * DIM;
  float a = b_lift[kd];
#pragma unroll 8
  for (int d = 0; d < DIM; ++d)
    a = fmaf((xr[d] - mu[d]) * __builtin_amdgcn_rcpf(sigma[d]), W_lift[d * KD + kd], a);
  a = fmaf((salv - mu[64]) * __builtin_amdgcn_rcpf(sigma[64]), W_lift[64 * KD + kd], a);
  a = fmaf(((float)idx / (float)N - mu[65]) * __builtin_amdgcn_rcpf(sigma[65]),
           W_lift[65 * KD + kd], a);
  lifted[p][kd] = a;
  __syncthreads();

  // project: 16 points x 512 dims; thread t does float2 of each point
  const float2* __restrict__ Wp2 = (const float2*)W_proj;
  const float2 bp = ((const float2*)b_proj)[t];
#pragma unroll 1
  for (int p2 = 0; p2 < MP; ++p2) {
    float2 o = bp;
#pragma unroll
    for (int c = 0; c < KD; ++c) {
      const float2 w = Wp2[c * 256 + t];
      o.x = fmaf(lifted[p2][c], w.x, o.x);
      o.y = fmaf(lifted[p2][c], w.y, o.y);
    }
    ((float2*)(tokens + ((size_t)b * MP + p2) * DM))[t] = o;
  }
}

extern "C" void kernel_launch(void* const* d_in, const int* in_sizes, int n_in,
                              void* d_out, int out_size, void* d_ws, size_t ws_size,
                              hipStream_t stream) {
  const float* x      = (const float*)d_in[0];
  const float* W1     = (const float*)d_in[1];
  const float* b1     = (const float*)d_in[2];
  // d_in[3] = w_e (unused by the reference outputs)
  const float* w_s    = (const float*)d_in[4];
  const float* W_lift = (const float*)d_in[5];
  const float* b_lift = (const float*)d_in[6];
  const float* W_proj = (const float*)d_in[7];
  const float* b_proj = (const float*)d_in[8];
  const float* mu     = (const float*)d_in[9];
  const float* sigma  = (const float*)d_in[10];

  float* tokens = (float*)d_out;                       // [B, MP, DM]
  float* ystar  = (float*)d_out + (size_t)B * MP * DM; // [B, N] (saliency staged here)

  // workspace layout (floats)
  float* cmax    = (float*)d_ws + 1024;        // 256
  float* csum    = (float*)d_ws + 1280;        // 256
  float* cval    = (float*)d_ws + 1600;        // 4096
  int*   cidx    = (int*)d_ws + 5696;          // 4096

  k_saliency<<<GRID_SAL, 256, 0, stream>>>(x, W1, b1, w_s, ystar);
  k_chunk<<<(B * N) / 2048, 256, 0, stream>>>(ystar, cmax, csum, cval, cidx);
  k_final<<<2048 + 32, 256, 0, stream>>>(ystar, cmax, csum, cval, cidx, x,
                                         W_lift, b_lift, W_proj, b_proj,
                                         mu, sigma, tokens);
}